// Round 12
// baseline (197.498 us; speedup 1.0000x reference)
//
#include <hip/hip_runtime.h>
#include <hip/hip_bf16.h>

// ExpansionContrastModule on MI355X.
// b=2, C=32, H=W=256, kv grid 64x64, shifts (1,2,4), 8 diff kernels.
// ROUND: revert fusion; k2 split into k2m (map producer, 128 blocks) + k2r (reduce,
// j-loop byte-identical to round-10 k2). qmap/kmap alias v's tail (freed before k3a
// writes v). K1/K3a/K3b byte-identical to round-10 passing.
// Pipeline: k1 -> k2m -> k2r -> k3a -> k3b.

#define CC 32
#define HW 256
#define KVW 64

// ---------------- K1: 5x5 stride-4 pad-2 conv + bias -> kv [2,32,64,64] ----------------
__global__ __launch_bounds__(256, 2) void k1_trans(const float* __restrict__ cen,
                                                   const float* __restrict__ tW,
                                                   const float* __restrict__ tB,
                                                   float* __restrict__ kv) {
  int bid = blockIdx.x;
  int b = bid >> 8, cog = (bid >> 6) & 3, y = bid & 63;
  int tid = threadIdx.x;
  int x = tid & 63;
  int w = __builtin_amdgcn_readfirstlane(tid >> 6);
  int co0 = cog * 8 + w * 2;  // wave-uniform

  float acc0 = 0.f, acc1 = 0.f;
  const float4 z4 = {0.f, 0.f, 0.f, 0.f};

  int roff[5];
  bool rok[5];
#pragma unroll
  for (int r = 0; r < 5; r++) {
    int row = 4 * y - 2 + r;
    rok[r] = (row >= 0);
    roff[r] = (row < 0 ? 0 : row) * HW;
  }

  for (int ci = 0; ci < CC; ci += 4) {
    const float* pc[4];
#pragma unroll
    for (int c = 0; c < 4; c++) pc[c] = cen + (size_t)(b * CC + ci + c) * 65536 + 4 * x;
    float4 A[4][5], B[4][5];
#pragma unroll
    for (int c = 0; c < 4; c++) {
#pragma unroll
      for (int r = 0; r < 5; r++) {
        A[c][r] = (x > 0) ? *(const float4*)(pc[c] + roff[r] - 4) : z4;  // 4x-4..4x-1
        B[c][r] = *(const float4*)(pc[c] + roff[r]);                     // 4x..4x+3
      }
    }
#pragma unroll
    for (int r = 0; r < 5; r++) {
      if (!rok[r]) continue;  // block-uniform (only y==0, r<2)
#pragma unroll
      for (int c = 0; c < 4; c++) {
        const float* wa = tW + (co0 * CC + ci + c) * 25 + r * 5;  // uniform -> s_load
        const float* wb = wa + CC * 25;                           // (co0+1, ci+c)
        acc0 += wa[0] * A[c][r].z + wa[1] * A[c][r].w + wa[2] * B[c][r].x +
                wa[3] * B[c][r].y + wa[4] * B[c][r].z;
        acc1 += wb[0] * A[c][r].z + wb[1] * A[c][r].w + wb[2] * B[c][r].x +
                wb[3] * B[c][r].y + wb[4] * B[c][r].z;
      }
    }
  }
  kv[((b * CC + co0) * KVW + y) * KVW + x] = acc0 + tB[co0];
  kv[((b * CC + co0 + 1) * KVW + y) * KVW + x] = acc1 + tB[co0 + 1];
}

// ---------------- K2m: q/k maps from kv (1x1 convs) ----------------
// grid 128 = b(2) x chunk(64); 256 thr = 4 waves; lane = px-in-chunk, wave = c-group(8).
// qmap[(b*32+c)*4096+px], kmap[((i*2+b)*32+c)*4096+px].
__global__ __launch_bounds__(256) void k2m_maps(const float* __restrict__ kv,
                                                const float* __restrict__ qW,
                                                const float* __restrict__ kW,
                                                float* __restrict__ qmap,
                                                float* __restrict__ kmap) {
  int bid = blockIdx.x;
  int b = bid >> 6, chunk = bid & 63;
  int tid = threadIdx.x;
  int lane = tid & 63;
  int cg = __builtin_amdgcn_readfirstlane(tid >> 6);  // wave-uniform c group (8 c)
  int px = chunk * 64 + lane;

  float cr[CC];
#pragma unroll
  for (int ci = 0; ci < CC; ci++) cr[ci] = kv[(b * CC + ci) * 4096 + px];

#pragma unroll
  for (int cc = 0; cc < 8; cc++) {
    int c = cg * 8 + cc;
    const float* qp = qW + c * CC;  // uniform -> s_load
    float q = 0.f;
#pragma unroll
    for (int ci = 0; ci < CC; ci++) q += qp[ci] * cr[ci];
    qmap[(b * CC + c) * 4096 + px] = q;
#pragma unroll
    for (int i = 0; i < 3; i++) {
      const float* kp = kW + (i * CC + c) * CC;  // uniform -> s_load
      float k = 0.f;
#pragma unroll
      for (int ci = 0; ci < CC; ci++) k += kp[ci] * cr[ci];
      kmap[((i * 2 + b) * CC + c) * 4096 + px] = k;
    }
  }
}

// ---------------- K2r: scores [2,32,24] — j-loop byte-identical to round-10 k2 --------
__device__ inline float wred64(float v) {
#pragma unroll
  for (int off = 1; off < 64; off <<= 1) v += __shfl_xor(v, off);
  return v;
}

__global__ __launch_bounds__(1024) void k2r_scores(const float* __restrict__ qmap,
                                                   const float* __restrict__ kmap,
                                                   float* __restrict__ scores) {
  __shared__ alignas(16) float kl[3][4096];
  __shared__ float wred[16][52];
  __shared__ float srl[24];
  int bc = blockIdx.x;
  int b = bc >> 5, c = bc & 31;
  int tid = threadIdx.x;
  int lane = tid & 63, w = tid >> 6;  // w 0..15
  int xx = tid & 63;
  int ybase = tid >> 6;  // row base 0..15; thread's rows are r*16 + ybase

  // producer phase: coalesced copies from precomputed maps (same px mapping as before)
  float qreg[4];
#pragma unroll
  for (int r = 0; r < 4; r++)
    qreg[r] = qmap[(b * CC + c) * 4096 + r * 1024 + tid];  // row = r*16+ybase, col = xx
  for (int f = tid; f < 3072; f += 1024) {
    int i = f >> 10, p4 = (f & 1023) << 2;
    *(float4*)&kl[i][p4] =
        *(const float4*)(kmap + ((size_t)((i * 2 + b) * CC + c) << 12) + p4);
  }
  __syncthreads();

  float q2 = 0.f;
#pragma unroll
  for (int r = 0; r < 4; r++) q2 += qreg[r] * qreg[r];
  q2 = wred64(q2);
  if (lane == 0) wred[w][48] = q2;

  constexpr int DYt[8] = {-1, -1, -1, 0, 1, 1, 1, 0};
  constexpr int DXt[8] = {-1, 0, 1, 1, 1, 0, -1, -1};
#pragma unroll
  for (int j = 0; j < 24; j++) {
    const int i = j >> 3, n = j & 7, d = 1 << i;
    const int dy = DYt[n], dx = DXt[n];
    int xn = xx + dx * d;
    bool xok = (xn >= 0 && xn < KVW);
    float dacc = 0.f, macc = 0.f;
#pragma unroll
    for (int r = 0; r < 4; r++) {
      int yy = r * 16 + ybase;
      int px = yy * KVW + xx;
      float kc = kl[i][px];
      int yn = yy + dy * d;
      float kn = (xok && yn >= 0 && yn < KVW) ? kl[i][yn * KVW + xn] : 0.f;
      float df = kc - kn;
      dacc += qreg[r] * df;
      macc += df * df;
    }
    dacc = wred64(dacc);
    macc = wred64(macc);
    if (lane == 0) {
      wred[w][j] = dacc;
      wred[w][24 + j] = macc;
    }
  }
  __syncthreads();
  if (tid < 24) {
    float D = 0.f, M = 0.f, Q2 = 0.f;
    for (int w2 = 0; w2 < 16; w2++) {
      D += wred[w2][tid];
      M += wred[w2][24 + tid];
      Q2 += wred[w2][48];
    }
    float sr = D / (fmaxf(sqrtf(M), 1e-12f) * fmaxf(sqrtf(Q2), 1e-12f));
    srl[tid] = sr;
  }
  __syncthreads();
  if (tid < 24) {
    float r2 = 0.f;
    for (int j = 0; j < 24; j++) r2 += srl[j] * srl[j];
    float s = srl[tid] / fmaxf(sqrtf(r2), 1e-12f);
    scores[(b * CC + c) * 24 + tid] = s;
  }
}

// ---------------- K3a: v[i][b][c][px] = 1x1 conv value maps, bf16 (round-10 verbatim) --
__global__ __launch_bounds__(256) void k3a_values(const float* __restrict__ cen,
                                                  const float* __restrict__ vW,
                                                  __hip_bfloat16* __restrict__ v) {
  int bid = blockIdx.x;
  int b = bid >> 10, blk = bid & 1023;
  int tid = threadIdx.x;
  int lane = tid & 63;
  int cg = __builtin_amdgcn_readfirstlane(tid >> 6);  // wave-uniform c group (8 c each)
  int px = blk * 64 + lane;

  float cr[CC];
#pragma unroll
  for (int ci = 0; ci < CC; ci++) cr[ci] = cen[(b * CC + ci) * 65536 + px];

#pragma unroll
  for (int i = 0; i < 3; i++) {
#pragma unroll
    for (int cc = 0; cc < 8; cc++) {
      int c = cg * 8 + cc;
      const float* wp = vW + (i * CC + c) * CC;  // uniform -> s_load
      float a = 0.f;
#pragma unroll
      for (int ci = 0; ci < CC; ci++) a += wp[ci] * cr[ci];
      v[((i * 2 + b) * CC + c) * 65536 + px] = __float2bfloat16(a);
    }
  }
}

// ---------------- K3b: combine taps + out conv + BN + ReLU (round-10 verbatim) --------
__global__ __launch_bounds__(256) void k3b_combine(const __hip_bfloat16* __restrict__ v,
                                                   const float* __restrict__ scores,
                                                   const float* __restrict__ oW,
                                                   const float* __restrict__ gamma,
                                                   const float* __restrict__ beta,
                                                   const float* __restrict__ mean,
                                                   const float* __restrict__ var,
                                                   float* __restrict__ out) {
  __shared__ alignas(16) float vt[3 * 24 * 24 * 4];  // [i][r][col][cp] halo-4 tiles
  __shared__ alignas(16) float sl[27][32];           // 0..23: s[j][c]; 24..26: S_i[c]
  __shared__ alignas(16) float owl[32][32];          // [co][c]
  __shared__ float bns[32], bnb[32];

  int bid = blockIdx.x;
  int b = bid >> 8, tile = bid & 255;
  int ty = tile >> 4, tx = tile & 15;
  int tid = threadIdx.x;
  int ly = tid >> 4, lx = tid & 15;

  for (int f = tid; f < 24 * 32; f += 256) {
    int j = f >> 5, c = f & 31;
    sl[j][c] = scores[(b * CC + c) * 24 + j];
  }
  for (int f = tid; f < 1024; f += 256) owl[f >> 5][f & 31] = oW[f];
  if (tid < 32) {
    float inv = rsqrtf(var[tid] + 1e-5f);
    float sc = gamma[tid] * inv;
    bns[tid] = sc;
    bnb[tid] = beta[tid] - mean[tid] * sc;
  }
  __syncthreads();
  if (tid < 32) {
#pragma unroll
    for (int i = 0; i < 3; i++) {
      float s = 0.f;
      for (int n = 0; n < 8; n++) s += sl[i * 8 + n][tid];
      sl[24 + i][tid] = s;
    }
  }

  int ldsoff[4], pxoff[4], ibase[4];
  bool okp[4];
#pragma unroll
  for (int it = 0; it < 4; it++) {
    int p = tid + it * 256;
    bool act = (p < 864);
    int pp = act ? p : 0;
    int i = pp / 288;
    int rem = pp - i * 288;
    int r = rem / 12;
    int col = (rem - r * 12) * 2;
    int gy = ty * 16 + r - 4, gx = tx * 16 + col - 4;
    okp[it] = act && gy >= 0 && gy < HW && gx >= 0 && gx < HW;
    pxoff[it] = gy * HW + gx;
    ibase[it] = (i * 2 + b) * CC;
    ldsoff[it] = ((i * 24 + r) * 24 + col) * 4;
  }

  constexpr int DYt[8] = {-1, -1, -1, 0, 1, 1, 1, 0};
  constexpr int DXt[8] = {-1, 0, 1, 1, 1, 0, -1, -1};

  float acc[32];
#pragma unroll
  for (int co = 0; co < 32; co++) acc[co] = 0.f;

  unsigned int pf[4][4];
  const unsigned short* vs = (const unsigned short*)v;

#pragma unroll
  for (int it = 0; it < 4; it++)
#pragma unroll
    for (int cp = 0; cp < 4; cp++)
      pf[it][cp] = okp[it]
                       ? *(const unsigned int*)(vs + (((size_t)(ibase[it] + cp)) << 16) +
                                                pxoff[it])
                       : 0u;

  for (int cg = 0; cg < 8; cg++) {
    __syncthreads();
#pragma unroll
    for (int it = 0; it < 4; it++) {
      if (it == 3 && tid >= 96) continue;  // p >= 864
      float4 lo, hi;
      lo.x = __uint_as_float(pf[it][0] << 16);
      lo.y = __uint_as_float(pf[it][1] << 16);
      lo.z = __uint_as_float(pf[it][2] << 16);
      lo.w = __uint_as_float(pf[it][3] << 16);
      hi.x = __uint_as_float(pf[it][0] & 0xffff0000u);
      hi.y = __uint_as_float(pf[it][1] & 0xffff0000u);
      hi.z = __uint_as_float(pf[it][2] & 0xffff0000u);
      hi.w = __uint_as_float(pf[it][3] & 0xffff0000u);
      *(float4*)&vt[ldsoff[it]] = lo;
      *(float4*)&vt[ldsoff[it] + 4] = hi;
    }
    if (cg < 7) {
      int cb = (cg + 1) * 4;
#pragma unroll
      for (int it = 0; it < 4; it++)
#pragma unroll
        for (int cp = 0; cp < 4; cp++)
          pf[it][cp] = okp[it] ? *(const unsigned int*)(vs +
                                                        (((size_t)(ibase[it] + cb + cp))
                                                         << 16) +
                                                        pxoff[it])
                               : 0u;
    }
    __syncthreads();

    float4 pre = {0.f, 0.f, 0.f, 0.f};
#pragma unroll
    for (int i = 0; i < 3; i++) {
      const int d = 1 << i;
      float4 S4 = *(const float4*)&sl[24 + i][cg * 4];
      float4 ctr = *(const float4*)&vt[((i * 24 + (ly + 4)) * 24 + (lx + 4)) * 4];
      pre.x += S4.x * ctr.x;
      pre.y += S4.y * ctr.y;
      pre.z += S4.z * ctr.z;
      pre.w += S4.w * ctr.w;
#pragma unroll
      for (int n = 0; n < 8; n++) {
        float4 sj = *(const float4*)&sl[i * 8 + n][cg * 4];
        float4 nb = *(const float4*)&vt[((i * 24 + (ly + 4 + DYt[n] * d)) * 24 +
                                         (lx + 4 + DXt[n] * d)) * 4];
        pre.x -= sj.x * nb.x;
        pre.y -= sj.y * nb.y;
        pre.z -= sj.z * nb.z;
        pre.w -= sj.w * nb.w;
      }
    }
#pragma unroll
    for (int co = 0; co < 32; co++) {
      float4 ow = *(const float4*)&owl[co][cg * 4];
      acc[co] += ow.x * pre.x + ow.y * pre.y + ow.z * pre.z + ow.w * pre.w;
    }
  }

  int gy = ty * 16 + ly, gx = tx * 16 + lx;
#pragma unroll
  for (int co = 0; co < 32; co++) {
    float val = acc[co] * bns[co] + bnb[co];
    out[((size_t)(b * CC + co) << 16) + gy * HW + gx] = fmaxf(val, 0.f);
  }
}

extern "C" void kernel_launch(void* const* d_in, const int* in_sizes, int n_in,
                              void* d_out, int out_size, void* d_ws, size_t ws_size,
                              hipStream_t stream) {
  const float* cen = (const float*)d_in[0];
  const float* trans_W = (const float*)d_in[1];
  const float* trans_b = (const float*)d_in[2];
  const float* query_W = (const float*)d_in[3];
  const float* value_W = (const float*)d_in[4];
  const float* key_W = (const float*)d_in[5];
  const float* out_W = (const float*)d_in[6];
  const float* bn_gamma = (const float*)d_in[7];
  const float* bn_beta = (const float*)d_in[8];
  const float* bn_mean = (const float*)d_in[9];
  const float* bn_var = (const float*)d_in[10];
  float* out = (float*)d_out;

  // workspace layout — total footprint identical to round-10 (25,698,304 B):
  //   kv     [0,        524288)
  //   scores [524288,   530432)
  //   v      [532480,   25698304)  (bf16)
  //   qmap   [21504000, 22552576)  -- aliases v tail; consumed by k2r BEFORE k3a writes v
  //   kmap   [22552576, 25698304)  -- same
  float* kv = (float*)d_ws;
  float* scores = (float*)((char*)d_ws + 524288);
  __hip_bfloat16* v = (__hip_bfloat16*)((char*)d_ws + 532480);
  float* qmap = (float*)((char*)d_ws + 21504000);
  float* kmap = (float*)((char*)d_ws + 22552576);

  k1_trans<<<512, 256, 0, stream>>>(cen, trans_W, trans_b, kv);
  k2m_maps<<<128, 256, 0, stream>>>(kv, query_W, key_W, qmap, kmap);
  k2r_scores<<<64, 1024, 0, stream>>>(qmap, kmap, scores);
  k3a_values<<<2048, 256, 0, stream>>>(cen, value_W, v);  // clobbers qmap/kmap (ok)
  k3b_combine<<<512, 256, 0, stream>>>(v, scores, out_W, bn_gamma, bn_beta, bn_mean,
                                       bn_var, out);
}

// Round 13
// 186.790 us; speedup vs baseline: 1.0573x; 1.0573x over previous
//
#include <hip/hip_runtime.h>
#include <hip/hip_bf16.h>

// ExpansionContrastModule on MI355X.
// b=2, C=32, H=W=256, kv grid 64x64, shifts (1,2,4), 8 diff kernels.
// BISECT ROUND: revert k2 split (round-10 merged k2 restored verbatim); single change
// is k3a -> 2 px/thread with packed bf16-pair stores. K1/K2/K3b byte-identical to
// round-10 passing. Pipeline: k1 -> k2 -> k3a -> k3b.

#define CC 32
#define HW 256
#define KVW 64

// ---------------- K1: 5x5 stride-4 pad-2 conv + bias -> kv [2,32,64,64] ----------------
__global__ __launch_bounds__(256, 2) void k1_trans(const float* __restrict__ cen,
                                                   const float* __restrict__ tW,
                                                   const float* __restrict__ tB,
                                                   float* __restrict__ kv) {
  int bid = blockIdx.x;
  int b = bid >> 8, cog = (bid >> 6) & 3, y = bid & 63;
  int tid = threadIdx.x;
  int x = tid & 63;
  int w = __builtin_amdgcn_readfirstlane(tid >> 6);
  int co0 = cog * 8 + w * 2;  // wave-uniform

  float acc0 = 0.f, acc1 = 0.f;
  const float4 z4 = {0.f, 0.f, 0.f, 0.f};

  int roff[5];
  bool rok[5];
#pragma unroll
  for (int r = 0; r < 5; r++) {
    int row = 4 * y - 2 + r;
    rok[r] = (row >= 0);
    roff[r] = (row < 0 ? 0 : row) * HW;
  }

  for (int ci = 0; ci < CC; ci += 4) {
    const float* pc[4];
#pragma unroll
    for (int c = 0; c < 4; c++) pc[c] = cen + (size_t)(b * CC + ci + c) * 65536 + 4 * x;
    float4 A[4][5], B[4][5];
#pragma unroll
    for (int c = 0; c < 4; c++) {
#pragma unroll
      for (int r = 0; r < 5; r++) {
        A[c][r] = (x > 0) ? *(const float4*)(pc[c] + roff[r] - 4) : z4;  // 4x-4..4x-1
        B[c][r] = *(const float4*)(pc[c] + roff[r]);                     // 4x..4x+3
      }
    }
#pragma unroll
    for (int r = 0; r < 5; r++) {
      if (!rok[r]) continue;  // block-uniform (only y==0, r<2)
#pragma unroll
      for (int c = 0; c < 4; c++) {
        const float* wa = tW + (co0 * CC + ci + c) * 25 + r * 5;  // uniform -> s_load
        const float* wb = wa + CC * 25;                           // (co0+1, ci+c)
        acc0 += wa[0] * A[c][r].z + wa[1] * A[c][r].w + wa[2] * B[c][r].x +
                wa[3] * B[c][r].y + wa[4] * B[c][r].z;
        acc1 += wb[0] * A[c][r].z + wb[1] * A[c][r].w + wb[2] * B[c][r].x +
                wb[3] * B[c][r].y + wb[4] * B[c][r].z;
      }
    }
  }
  kv[((b * CC + co0) * KVW + y) * KVW + x] = acc0 + tB[co0];
  kv[((b * CC + co0 + 1) * KVW + y) * KVW + x] = acc1 + tB[co0 + 1];
}

// ---------------- K2: scores [2,32,24] — 1024 threads, 4 px/thread (round-10 verbatim) -
__device__ inline float wred64(float v) {
#pragma unroll
  for (int off = 1; off < 64; off <<= 1) v += __shfl_xor(v, off);
  return v;
}

__global__ __launch_bounds__(1024) void k2_scores(const float* __restrict__ kv,
                                                  const float* __restrict__ qW,
                                                  const float* __restrict__ kW,
                                                  float* __restrict__ scores) {
  __shared__ alignas(16) float kl[3][4096];
  __shared__ float wred[16][52];
  __shared__ float srl[24];
  int bc = blockIdx.x;
  int b = bc >> 5, c = bc & 31;
  int tid = threadIdx.x;
  int lane = tid & 63, w = tid >> 6;  // w 0..15
  int xx = tid & 63;
  int ybase = tid >> 6;  // row base 0..15; thread's rows are r*16 + ybase

  float qreg[4];
#pragma unroll
  for (int r = 0; r < 4; r++) {
    int px = r * 1024 + tid;  // row = r*16 + ybase, col = xx
    float q = 0.f, k0 = 0.f, k1 = 0.f, k2 = 0.f;
    for (int ci = 0; ci < CC; ci++) {
      float val = kv[(b * CC + ci) * 4096 + px];
      q += qW[c * CC + ci] * val;
      k0 += kW[(0 * CC + c) * CC + ci] * val;
      k1 += kW[(1 * CC + c) * CC + ci] * val;
      k2 += kW[(2 * CC + c) * CC + ci] * val;
    }
    qreg[r] = q;
    kl[0][px] = k0;
    kl[1][px] = k1;
    kl[2][px] = k2;
  }
  __syncthreads();

  float q2 = 0.f;
#pragma unroll
  for (int r = 0; r < 4; r++) q2 += qreg[r] * qreg[r];
  q2 = wred64(q2);
  if (lane == 0) wred[w][48] = q2;

  constexpr int DYt[8] = {-1, -1, -1, 0, 1, 1, 1, 0};
  constexpr int DXt[8] = {-1, 0, 1, 1, 1, 0, -1, -1};
#pragma unroll
  for (int j = 0; j < 24; j++) {
    const int i = j >> 3, n = j & 7, d = 1 << i;
    const int dy = DYt[n], dx = DXt[n];
    int xn = xx + dx * d;
    bool xok = (xn >= 0 && xn < KVW);
    float dacc = 0.f, macc = 0.f;
#pragma unroll
    for (int r = 0; r < 4; r++) {
      int yy = r * 16 + ybase;
      int px = yy * KVW + xx;
      float kc = kl[i][px];
      int yn = yy + dy * d;
      float kn = (xok && yn >= 0 && yn < KVW) ? kl[i][yn * KVW + xn] : 0.f;
      float df = kc - kn;
      dacc += qreg[r] * df;
      macc += df * df;
    }
    dacc = wred64(dacc);
    macc = wred64(macc);
    if (lane == 0) {
      wred[w][j] = dacc;
      wred[w][24 + j] = macc;
    }
  }
  __syncthreads();
  if (tid < 24) {
    float D = 0.f, M = 0.f, Q2 = 0.f;
    for (int w2 = 0; w2 < 16; w2++) {
      D += wred[w2][tid];
      M += wred[w2][24 + tid];
      Q2 += wred[w2][48];
    }
    float sr = D / (fmaxf(sqrtf(M), 1e-12f) * fmaxf(sqrtf(Q2), 1e-12f));
    srl[tid] = sr;
  }
  __syncthreads();
  if (tid < 24) {
    float r2 = 0.f;
    for (int j = 0; j < 24; j++) r2 += srl[j] * srl[j];
    float s = srl[tid] / fmaxf(sqrtf(r2), 1e-12f);
    scores[(b * CC + c) * 24 + tid] = s;
  }
}

// ---------------- K3a: v[i][b][c][px], bf16, 2 px/thread + packed pair stores ----------
__global__ __launch_bounds__(256) void k3a_values(const float* __restrict__ cen,
                                                  const float* __restrict__ vW,
                                                  __hip_bfloat16* __restrict__ v) {
  int bid = blockIdx.x;  // 1024 = b(2) x blk(512)
  int b = bid >> 9, blk = bid & 511;
  int tid = threadIdx.x;
  int lane = tid & 63;
  int cg = __builtin_amdgcn_readfirstlane(tid >> 6);  // wave-uniform c group (8 c)
  int px = blk * 128 + lane * 2;

  float2 cr[CC];
#pragma unroll
  for (int ci = 0; ci < CC; ci++)
    cr[ci] = *(const float2*)(cen + (size_t)(b * CC + ci) * 65536 + px);

#pragma unroll
  for (int i = 0; i < 3; i++) {
#pragma unroll
    for (int cc = 0; cc < 8; cc++) {
      int c = cg * 8 + cc;
      const float* wp = vW + (i * CC + c) * CC;  // uniform -> s_load
      float a0 = 0.f, a1 = 0.f;
#pragma unroll
      for (int ci = 0; ci < CC; ci++) {
        a0 += wp[ci] * cr[ci].x;
        a1 += wp[ci] * cr[ci].y;
      }
      __hip_bfloat16 h0 = __float2bfloat16(a0);
      __hip_bfloat16 h1 = __float2bfloat16(a1);
      unsigned int pk = (unsigned int)(*(unsigned short*)&h0) |
                        ((unsigned int)(*(unsigned short*)&h1) << 16);
      *(unsigned int*)((unsigned short*)v + (((size_t)((i * 2 + b) * CC + c)) << 16) +
                       px) = pk;
    }
  }
}

// ---------------- K3b: combine taps + out conv + BN + ReLU (round-10 verbatim) --------
__global__ __launch_bounds__(256) void k3b_combine(const __hip_bfloat16* __restrict__ v,
                                                   const float* __restrict__ scores,
                                                   const float* __restrict__ oW,
                                                   const float* __restrict__ gamma,
                                                   const float* __restrict__ beta,
                                                   const float* __restrict__ mean,
                                                   const float* __restrict__ var,
                                                   float* __restrict__ out) {
  __shared__ alignas(16) float vt[3 * 24 * 24 * 4];  // [i][r][col][cp] halo-4 tiles
  __shared__ alignas(16) float sl[27][32];           // 0..23: s[j][c]; 24..26: S_i[c]
  __shared__ alignas(16) float owl[32][32];          // [co][c]
  __shared__ float bns[32], bnb[32];

  int bid = blockIdx.x;
  int b = bid >> 8, tile = bid & 255;
  int ty = tile >> 4, tx = tile & 15;
  int tid = threadIdx.x;
  int ly = tid >> 4, lx = tid & 15;

  for (int f = tid; f < 24 * 32; f += 256) {
    int j = f >> 5, c = f & 31;
    sl[j][c] = scores[(b * CC + c) * 24 + j];
  }
  for (int f = tid; f < 1024; f += 256) owl[f >> 5][f & 31] = oW[f];
  if (tid < 32) {
    float inv = rsqrtf(var[tid] + 1e-5f);
    float sc = gamma[tid] * inv;
    bns[tid] = sc;
    bnb[tid] = beta[tid] - mean[tid] * sc;
  }
  __syncthreads();
  if (tid < 32) {
#pragma unroll
    for (int i = 0; i < 3; i++) {
      float s = 0.f;
      for (int n = 0; n < 8; n++) s += sl[i * 8 + n][tid];
      sl[24 + i][tid] = s;
    }
  }

  int ldsoff[4], pxoff[4], ibase[4];
  bool okp[4];
#pragma unroll
  for (int it = 0; it < 4; it++) {
    int p = tid + it * 256;
    bool act = (p < 864);
    int pp = act ? p : 0;
    int i = pp / 288;
    int rem = pp - i * 288;
    int r = rem / 12;
    int col = (rem - r * 12) * 2;
    int gy = ty * 16 + r - 4, gx = tx * 16 + col - 4;
    okp[it] = act && gy >= 0 && gy < HW && gx >= 0 && gx < HW;
    pxoff[it] = gy * HW + gx;
    ibase[it] = (i * 2 + b) * CC;
    ldsoff[it] = ((i * 24 + r) * 24 + col) * 4;
  }

  constexpr int DYt[8] = {-1, -1, -1, 0, 1, 1, 1, 0};
  constexpr int DXt[8] = {-1, 0, 1, 1, 1, 0, -1, -1};

  float acc[32];
#pragma unroll
  for (int co = 0; co < 32; co++) acc[co] = 0.f;

  unsigned int pf[4][4];
  const unsigned short* vs = (const unsigned short*)v;

#pragma unroll
  for (int it = 0; it < 4; it++)
#pragma unroll
    for (int cp = 0; cp < 4; cp++)
      pf[it][cp] = okp[it]
                       ? *(const unsigned int*)(vs + (((size_t)(ibase[it] + cp)) << 16) +
                                                pxoff[it])
                       : 0u;

  for (int cg = 0; cg < 8; cg++) {
    __syncthreads();
#pragma unroll
    for (int it = 0; it < 4; it++) {
      if (it == 3 && tid >= 96) continue;  // p >= 864
      float4 lo, hi;
      lo.x = __uint_as_float(pf[it][0] << 16);
      lo.y = __uint_as_float(pf[it][1] << 16);
      lo.z = __uint_as_float(pf[it][2] << 16);
      lo.w = __uint_as_float(pf[it][3] << 16);
      hi.x = __uint_as_float(pf[it][0] & 0xffff0000u);
      hi.y = __uint_as_float(pf[it][1] & 0xffff0000u);
      hi.z = __uint_as_float(pf[it][2] & 0xffff0000u);
      hi.w = __uint_as_float(pf[it][3] & 0xffff0000u);
      *(float4*)&vt[ldsoff[it]] = lo;
      *(float4*)&vt[ldsoff[it] + 4] = hi;
    }
    if (cg < 7) {
      int cb = (cg + 1) * 4;
#pragma unroll
      for (int it = 0; it < 4; it++)
#pragma unroll
        for (int cp = 0; cp < 4; cp++)
          pf[it][cp] = okp[it] ? *(const unsigned int*)(vs +
                                                        (((size_t)(ibase[it] + cb + cp))
                                                         << 16) +
                                                        pxoff[it])
                               : 0u;
    }
    __syncthreads();

    float4 pre = {0.f, 0.f, 0.f, 0.f};
#pragma unroll
    for (int i = 0; i < 3; i++) {
      const int d = 1 << i;
      float4 S4 = *(const float4*)&sl[24 + i][cg * 4];
      float4 ctr = *(const float4*)&vt[((i * 24 + (ly + 4)) * 24 + (lx + 4)) * 4];
      pre.x += S4.x * ctr.x;
      pre.y += S4.y * ctr.y;
      pre.z += S4.z * ctr.z;
      pre.w += S4.w * ctr.w;
#pragma unroll
      for (int n = 0; n < 8; n++) {
        float4 sj = *(const float4*)&sl[i * 8 + n][cg * 4];
        float4 nb = *(const float4*)&vt[((i * 24 + (ly + 4 + DYt[n] * d)) * 24 +
                                         (lx + 4 + DXt[n] * d)) * 4];
        pre.x -= sj.x * nb.x;
        pre.y -= sj.y * nb.y;
        pre.z -= sj.z * nb.z;
        pre.w -= sj.w * nb.w;
      }
    }
#pragma unroll
    for (int co = 0; co < 32; co++) {
      float4 ow = *(const float4*)&owl[co][cg * 4];
      acc[co] += ow.x * pre.x + ow.y * pre.y + ow.z * pre.z + ow.w * pre.w;
    }
  }

  int gy = ty * 16 + ly, gx = tx * 16 + lx;
#pragma unroll
  for (int co = 0; co < 32; co++) {
    float val = acc[co] * bns[co] + bnb[co];
    out[((size_t)(b * CC + co) << 16) + gy * HW + gx] = fmaxf(val, 0.f);
  }
}

extern "C" void kernel_launch(void* const* d_in, const int* in_sizes, int n_in,
                              void* d_out, int out_size, void* d_ws, size_t ws_size,
                              hipStream_t stream) {
  const float* cen = (const float*)d_in[0];
  const float* trans_W = (const float*)d_in[1];
  const float* trans_b = (const float*)d_in[2];
  const float* query_W = (const float*)d_in[3];
  const float* value_W = (const float*)d_in[4];
  const float* key_W = (const float*)d_in[5];
  const float* out_W = (const float*)d_in[6];
  const float* bn_gamma = (const float*)d_in[7];
  const float* bn_beta = (const float*)d_in[8];
  const float* bn_mean = (const float*)d_in[9];
  const float* bn_var = (const float*)d_in[10];
  float* out = (float*)d_out;

  // workspace layout (identical to round-10 passing)
  float* kv = (float*)d_ws;                                            // 524,288 B
  float* scores = (float*)((char*)d_ws + 524288);                      // 6,144 B
  __hip_bfloat16* v = (__hip_bfloat16*)((char*)d_ws + 524288 + 8192);  // 25,165,824 B

  k1_trans<<<512, 256, 0, stream>>>(cen, trans_W, trans_b, kv);
  k2_scores<<<64, 1024, 0, stream>>>(kv, query_W, key_W, scores);
  k3a_values<<<1024, 256, 0, stream>>>(cen, value_W, v);
  k3b_combine<<<512, 256, 0, stream>>>(v, scores, out_W, bn_gamma, bn_beta, bn_mean,
                                       bn_var, out);
}

// Round 14
// 177.114 us; speedup vs baseline: 1.1151x; 1.0546x over previous
//
#include <hip/hip_runtime.h>
#include <hip/hip_bf16.h>

// ExpansionContrastModule on MI355X.
// b=2, C=32, H=W=256, kv grid 64x64, shifts (1,2,4), 8 diff kernels.
// ROUND: k2 split over shift index i (192 blocks, full maps, NO spatial halo) + tiny
// finalize. j-loop body byte-identical to round-13 k2 with kl[i]->kl, d fixed.
// K1/K3a/K3b byte-identical to round-13 passing.
// Pipeline: k1 -> k2i -> k2f -> k3a -> k3b. pars aliases v tail (consumed before k3a).

#define CC 32
#define HW 256
#define KVW 64

// ---------------- K1: 5x5 stride-4 pad-2 conv + bias -> kv [2,32,64,64] ----------------
__global__ __launch_bounds__(256, 2) void k1_trans(const float* __restrict__ cen,
                                                   const float* __restrict__ tW,
                                                   const float* __restrict__ tB,
                                                   float* __restrict__ kv) {
  int bid = blockIdx.x;
  int b = bid >> 8, cog = (bid >> 6) & 3, y = bid & 63;
  int tid = threadIdx.x;
  int x = tid & 63;
  int w = __builtin_amdgcn_readfirstlane(tid >> 6);
  int co0 = cog * 8 + w * 2;  // wave-uniform

  float acc0 = 0.f, acc1 = 0.f;
  const float4 z4 = {0.f, 0.f, 0.f, 0.f};

  int roff[5];
  bool rok[5];
#pragma unroll
  for (int r = 0; r < 5; r++) {
    int row = 4 * y - 2 + r;
    rok[r] = (row >= 0);
    roff[r] = (row < 0 ? 0 : row) * HW;
  }

  for (int ci = 0; ci < CC; ci += 4) {
    const float* pc[4];
#pragma unroll
    for (int c = 0; c < 4; c++) pc[c] = cen + (size_t)(b * CC + ci + c) * 65536 + 4 * x;
    float4 A[4][5], B[4][5];
#pragma unroll
    for (int c = 0; c < 4; c++) {
#pragma unroll
      for (int r = 0; r < 5; r++) {
        A[c][r] = (x > 0) ? *(const float4*)(pc[c] + roff[r] - 4) : z4;  // 4x-4..4x-1
        B[c][r] = *(const float4*)(pc[c] + roff[r]);                     // 4x..4x+3
      }
    }
#pragma unroll
    for (int r = 0; r < 5; r++) {
      if (!rok[r]) continue;  // block-uniform (only y==0, r<2)
#pragma unroll
      for (int c = 0; c < 4; c++) {
        const float* wa = tW + (co0 * CC + ci + c) * 25 + r * 5;  // uniform -> s_load
        const float* wb = wa + CC * 25;                           // (co0+1, ci+c)
        acc0 += wa[0] * A[c][r].z + wa[1] * A[c][r].w + wa[2] * B[c][r].x +
                wa[3] * B[c][r].y + wa[4] * B[c][r].z;
        acc1 += wb[0] * A[c][r].z + wb[1] * A[c][r].w + wb[2] * B[c][r].x +
                wb[3] * B[c][r].y + wb[4] * B[c][r].z;
      }
    }
  }
  kv[((b * CC + co0) * KVW + y) * KVW + x] = acc0 + tB[co0];
  kv[((b * CC + co0 + 1) * KVW + y) * KVW + x] = acc1 + tB[co0 + 1];
}

// ---------------- K2i: per-(b,c,i) partials D[8], M[8], Q2 ----------------
__device__ inline float wred64(float v) {
#pragma unroll
  for (int off = 1; off < 64; off <<= 1) v += __shfl_xor(v, off);
  return v;
}

__global__ __launch_bounds__(1024) void k2i_partial(const float* __restrict__ kv,
                                                    const float* __restrict__ qW,
                                                    const float* __restrict__ kW,
                                                    float* __restrict__ pars) {
  __shared__ alignas(16) float kl[4096];  // full 64x64 k_i map (16 KB), no halo
  __shared__ float wredl[16][18];         // per-wave: D[8], M[8], Q2[16]
  int bid = blockIdx.x;  // 192 = bc(64) * 3 + i
  int bc = bid / 3, i = bid - bc * 3;
  int b = bc >> 5, c = bc & 31;
  int tid = threadIdx.x;
  int lane = tid & 63, w = tid >> 6;  // w 0..15
  int xx = tid & 63;
  int ybase = tid >> 6;  // thread's rows are r*16 + ybase

  float qreg[4];
#pragma unroll
  for (int r = 0; r < 4; r++) {
    int px = r * 1024 + tid;  // row = r*16 + ybase, col = xx
    float q = 0.f, kk = 0.f;
    for (int ci = 0; ci < CC; ci++) {
      float val = kv[(b * CC + ci) * 4096 + px];
      q += qW[c * CC + ci] * val;
      kk += kW[(i * CC + c) * CC + ci] * val;
    }
    qreg[r] = q;
    kl[px] = kk;
  }
  __syncthreads();

  float q2 = 0.f;
#pragma unroll
  for (int r = 0; r < 4; r++) q2 += qreg[r] * qreg[r];
  q2 = wred64(q2);
  if (lane == 0) wredl[w][16] = q2;

  constexpr int DYt[8] = {-1, -1, -1, 0, 1, 1, 1, 0};
  constexpr int DXt[8] = {-1, 0, 1, 1, 1, 0, -1, -1};
  const int d = 1 << i;
#pragma unroll
  for (int n = 0; n < 8; n++) {
    const int dy = DYt[n], dx = DXt[n];
    int xn = xx + dx * d;
    bool xok = (xn >= 0 && xn < KVW);
    float dacc = 0.f, macc = 0.f;
#pragma unroll
    for (int r = 0; r < 4; r++) {
      int yy = r * 16 + ybase;
      int px = yy * KVW + xx;
      float kc = kl[px];
      int yn = yy + dy * d;
      float kn = (xok && yn >= 0 && yn < KVW) ? kl[yn * KVW + xn] : 0.f;
      float df = kc - kn;
      dacc += qreg[r] * df;
      macc += df * df;
    }
    dacc = wred64(dacc);
    macc = wred64(macc);
    if (lane == 0) {
      wredl[w][n] = dacc;
      wredl[w][8 + n] = macc;
    }
  }
  __syncthreads();

  float* pp = pars + (size_t)bid * 32;
  if (tid < 8) {
    float D = 0.f, M = 0.f;
    for (int w2 = 0; w2 < 16; w2++) {
      D += wredl[w2][tid];
      M += wredl[w2][8 + tid];
    }
    pp[tid] = D;
    pp[8 + tid] = M;
  }
  if (tid == 0) {
    float Q = 0.f;
    for (int w2 = 0; w2 < 16; w2++) Q += wredl[w2][16];
    pp[16] = Q;
  }
}

// ---------------- K2f: finalize scores [2,32,24] (verified normalization tail) --------
__global__ __launch_bounds__(64) void k2f_finalize(const float* __restrict__ pars,
                                                   float* __restrict__ scores) {
  __shared__ float srl[24];
  int bc = blockIdx.x;  // 64 = b*32 + c
  int t = threadIdx.x;
  if (t < 24) {
    int i = t >> 3, n = t & 7;
    const float* pp = pars + (size_t)(bc * 3 + i) * 32;
    float D = pp[n];
    float M = pp[8 + n];
    float Q = pars[(size_t)(bc * 3) * 32 + 16];  // Q2 identical across i; use i=0's
    float sr = D / (fmaxf(sqrtf(M), 1e-12f) * fmaxf(sqrtf(Q), 1e-12f));
    srl[t] = sr;
  }
  __syncthreads();
  if (t < 24) {
    float r2 = 0.f;
    for (int j = 0; j < 24; j++) r2 += srl[j] * srl[j];
    scores[bc * 24 + t] = srl[t] / fmaxf(sqrtf(r2), 1e-12f);
  }
}

// ---------------- K3a: v[i][b][c][px], bf16, 2 px/thread (round-13 verbatim) ----------
__global__ __launch_bounds__(256) void k3a_values(const float* __restrict__ cen,
                                                  const float* __restrict__ vW,
                                                  __hip_bfloat16* __restrict__ v) {
  int bid = blockIdx.x;  // 1024 = b(2) x blk(512)
  int b = bid >> 9, blk = bid & 511;
  int tid = threadIdx.x;
  int lane = tid & 63;
  int cg = __builtin_amdgcn_readfirstlane(tid >> 6);  // wave-uniform c group (8 c)
  int px = blk * 128 + lane * 2;

  float2 cr[CC];
#pragma unroll
  for (int ci = 0; ci < CC; ci++)
    cr[ci] = *(const float2*)(cen + (size_t)(b * CC + ci) * 65536 + px);

#pragma unroll
  for (int i = 0; i < 3; i++) {
#pragma unroll
    for (int cc = 0; cc < 8; cc++) {
      int c = cg * 8 + cc;
      const float* wp = vW + (i * CC + c) * CC;  // uniform -> s_load
      float a0 = 0.f, a1 = 0.f;
#pragma unroll
      for (int ci = 0; ci < CC; ci++) {
        a0 += wp[ci] * cr[ci].x;
        a1 += wp[ci] * cr[ci].y;
      }
      __hip_bfloat16 h0 = __float2bfloat16(a0);
      __hip_bfloat16 h1 = __float2bfloat16(a1);
      unsigned int pk = (unsigned int)(*(unsigned short*)&h0) |
                        ((unsigned int)(*(unsigned short*)&h1) << 16);
      *(unsigned int*)((unsigned short*)v + (((size_t)((i * 2 + b) * CC + c)) << 16) +
                       px) = pk;
    }
  }
}

// ---------------- K3b: combine taps + out conv + BN + ReLU (round-13 verbatim) --------
__global__ __launch_bounds__(256) void k3b_combine(const __hip_bfloat16* __restrict__ v,
                                                   const float* __restrict__ scores,
                                                   const float* __restrict__ oW,
                                                   const float* __restrict__ gamma,
                                                   const float* __restrict__ beta,
                                                   const float* __restrict__ mean,
                                                   const float* __restrict__ var,
                                                   float* __restrict__ out) {
  __shared__ alignas(16) float vt[3 * 24 * 24 * 4];  // [i][r][col][cp] halo-4 tiles
  __shared__ alignas(16) float sl[27][32];           // 0..23: s[j][c]; 24..26: S_i[c]
  __shared__ alignas(16) float owl[32][32];          // [co][c]
  __shared__ float bns[32], bnb[32];

  int bid = blockIdx.x;
  int b = bid >> 8, tile = bid & 255;
  int ty = tile >> 4, tx = tile & 15;
  int tid = threadIdx.x;
  int ly = tid >> 4, lx = tid & 15;

  for (int f = tid; f < 24 * 32; f += 256) {
    int j = f >> 5, c = f & 31;
    sl[j][c] = scores[(b * CC + c) * 24 + j];
  }
  for (int f = tid; f < 1024; f += 256) owl[f >> 5][f & 31] = oW[f];
  if (tid < 32) {
    float inv = rsqrtf(var[tid] + 1e-5f);
    float sc = gamma[tid] * inv;
    bns[tid] = sc;
    bnb[tid] = beta[tid] - mean[tid] * sc;
  }
  __syncthreads();
  if (tid < 32) {
#pragma unroll
    for (int i = 0; i < 3; i++) {
      float s = 0.f;
      for (int n = 0; n < 8; n++) s += sl[i * 8 + n][tid];
      sl[24 + i][tid] = s;
    }
  }

  int ldsoff[4], pxoff[4], ibase[4];
  bool okp[4];
#pragma unroll
  for (int it = 0; it < 4; it++) {
    int p = tid + it * 256;
    bool act = (p < 864);
    int pp = act ? p : 0;
    int i = pp / 288;
    int rem = pp - i * 288;
    int r = rem / 12;
    int col = (rem - r * 12) * 2;
    int gy = ty * 16 + r - 4, gx = tx * 16 + col - 4;
    okp[it] = act && gy >= 0 && gy < HW && gx >= 0 && gx < HW;
    pxoff[it] = gy * HW + gx;
    ibase[it] = (i * 2 + b) * CC;
    ldsoff[it] = ((i * 24 + r) * 24 + col) * 4;
  }

  constexpr int DYt[8] = {-1, -1, -1, 0, 1, 1, 1, 0};
  constexpr int DXt[8] = {-1, 0, 1, 1, 1, 0, -1, -1};

  float acc[32];
#pragma unroll
  for (int co = 0; co < 32; co++) acc[co] = 0.f;

  unsigned int pf[4][4];
  const unsigned short* vs = (const unsigned short*)v;

#pragma unroll
  for (int it = 0; it < 4; it++)
#pragma unroll
    for (int cp = 0; cp < 4; cp++)
      pf[it][cp] = okp[it]
                       ? *(const unsigned int*)(vs + (((size_t)(ibase[it] + cp)) << 16) +
                                                pxoff[it])
                       : 0u;

  for (int cg = 0; cg < 8; cg++) {
    __syncthreads();
#pragma unroll
    for (int it = 0; it < 4; it++) {
      if (it == 3 && tid >= 96) continue;  // p >= 864
      float4 lo, hi;
      lo.x = __uint_as_float(pf[it][0] << 16);
      lo.y = __uint_as_float(pf[it][1] << 16);
      lo.z = __uint_as_float(pf[it][2] << 16);
      lo.w = __uint_as_float(pf[it][3] << 16);
      hi.x = __uint_as_float(pf[it][0] & 0xffff0000u);
      hi.y = __uint_as_float(pf[it][1] & 0xffff0000u);
      hi.z = __uint_as_float(pf[it][2] & 0xffff0000u);
      hi.w = __uint_as_float(pf[it][3] & 0xffff0000u);
      *(float4*)&vt[ldsoff[it]] = lo;
      *(float4*)&vt[ldsoff[it] + 4] = hi;
    }
    if (cg < 7) {
      int cb = (cg + 1) * 4;
#pragma unroll
      for (int it = 0; it < 4; it++)
#pragma unroll
        for (int cp = 0; cp < 4; cp++)
          pf[it][cp] = okp[it] ? *(const unsigned int*)(vs +
                                                        (((size_t)(ibase[it] + cb + cp))
                                                         << 16) +
                                                        pxoff[it])
                               : 0u;
    }
    __syncthreads();

    float4 pre = {0.f, 0.f, 0.f, 0.f};
#pragma unroll
    for (int i = 0; i < 3; i++) {
      const int d = 1 << i;
      float4 S4 = *(const float4*)&sl[24 + i][cg * 4];
      float4 ctr = *(const float4*)&vt[((i * 24 + (ly + 4)) * 24 + (lx + 4)) * 4];
      pre.x += S4.x * ctr.x;
      pre.y += S4.y * ctr.y;
      pre.z += S4.z * ctr.z;
      pre.w += S4.w * ctr.w;
#pragma unroll
      for (int n = 0; n < 8; n++) {
        float4 sj = *(const float4*)&sl[i * 8 + n][cg * 4];
        float4 nb = *(const float4*)&vt[((i * 24 + (ly + 4 + DYt[n] * d)) * 24 +
                                         (lx + 4 + DXt[n] * d)) * 4];
        pre.x -= sj.x * nb.x;
        pre.y -= sj.y * nb.y;
        pre.z -= sj.z * nb.z;
        pre.w -= sj.w * nb.w;
      }
    }
#pragma unroll
    for (int co = 0; co < 32; co++) {
      float4 ow = *(const float4*)&owl[co][cg * 4];
      acc[co] += ow.x * pre.x + ow.y * pre.y + ow.z * pre.z + ow.w * pre.w;
    }
  }

  int gy = ty * 16 + ly, gx = tx * 16 + lx;
#pragma unroll
  for (int co = 0; co < 32; co++) {
    float val = acc[co] * bns[co] + bnb[co];
    out[((size_t)(b * CC + co) << 16) + gy * HW + gx] = fmaxf(val, 0.f);
  }
}

extern "C" void kernel_launch(void* const* d_in, const int* in_sizes, int n_in,
                              void* d_out, int out_size, void* d_ws, size_t ws_size,
                              hipStream_t stream) {
  const float* cen = (const float*)d_in[0];
  const float* trans_W = (const float*)d_in[1];
  const float* trans_b = (const float*)d_in[2];
  const float* query_W = (const float*)d_in[3];
  const float* value_W = (const float*)d_in[4];
  const float* key_W = (const float*)d_in[5];
  const float* out_W = (const float*)d_in[6];
  const float* bn_gamma = (const float*)d_in[7];
  const float* bn_beta = (const float*)d_in[8];
  const float* bn_mean = (const float*)d_in[9];
  const float* bn_var = (const float*)d_in[10];
  float* out = (float*)d_out;

  // workspace layout — total footprint identical to round-13 (25,698,304 B):
  //   kv     [0,        524288)
  //   scores [524288,   530432)
  //   v      [532480,   25698304)  (bf16)
  //   pars   [25673728, 25698304)  -- aliases v tail (192*32 floats = 24 KB);
  //                                   consumed by k2f BEFORE k3a overwrites v.
  float* kv = (float*)d_ws;
  float* scores = (float*)((char*)d_ws + 524288);
  __hip_bfloat16* v = (__hip_bfloat16*)((char*)d_ws + 532480);
  float* pars = (float*)((char*)d_ws + 25673728);

  k1_trans<<<512, 256, 0, stream>>>(cen, trans_W, trans_b, kv);
  k2i_partial<<<192, 1024, 0, stream>>>(kv, query_W, key_W, pars);
  k2f_finalize<<<64, 64, 0, stream>>>(pars, scores);
  k3a_values<<<1024, 256, 0, stream>>>(cen, value_W, v);  // clobbers pars (ok)
  k3b_combine<<<512, 256, 0, stream>>>(v, scores, out_W, bn_gamma, bn_beta, bn_mean,
                                       bn_var, out);
}

// Round 15
// 173.159 us; speedup vs baseline: 1.1406x; 1.0228x over previous
//
#include <hip/hip_runtime.h>
#include <hip/hip_bf16.h>

// ExpansionContrastModule on MI355X.
// b=2, C=32, H=W=256, kv grid 64x64, shifts (1,2,4), 8 diff kernels.
// BISECT ROUND: only K1 changed — ci-range split across waves (wave = co-pair x ci-half,
// 160 tap loads/wave instead of 320, LDS partial combine). Grid 1024.
// K2i/K2f/K3a/K3b byte-identical to round-14 passing.
// Pipeline: k1 -> k2i -> k2f -> k3a -> k3b. pars aliases v tail (consumed before k3a).

#define CC 32
#define HW 256
#define KVW 64

// ---------------- K1: 5x5 stride-4 pad-2 conv + bias -> kv [2,32,64,64] ----------------
// grid 1024 = b(2) x cog(8) x y(64); 4 waves: wave w -> co pair cog*4 + (w>>1)*2,
// ci half (w&1)*16. ci-half-1 waves write partials to LDS; half-0 waves combine+store.
__global__ __launch_bounds__(256, 2) void k1_trans(const float* __restrict__ cen,
                                                   const float* __restrict__ tW,
                                                   const float* __restrict__ tB,
                                                   float* __restrict__ kv) {
  __shared__ alignas(16) float part[2][2][64];  // [copair][acc-sub][x], 2 KB
  int bid = blockIdx.x;
  int b = bid >> 9, cog = (bid >> 6) & 7, y = bid & 63;
  int tid = threadIdx.x;
  int x = tid & 63;
  int w = __builtin_amdgcn_readfirstlane(tid >> 6);
  int copair = w >> 1;           // wave-uniform, 0..1
  int cihalf = w & 1;            // wave-uniform, 0..1
  int co0 = cog * 4 + copair * 2;  // this wave's co pair (co0, co0+1)
  int ci0 = cihalf * 16;           // this wave's ci range [ci0, ci0+16)

  float acc0 = 0.f, acc1 = 0.f;
  const float4 z4 = {0.f, 0.f, 0.f, 0.f};

  // Output row y taps input rows 4y-2+r, r=0..4. Max row 254 (in bounds);
  // only y==0 has rows -2,-1 -> clamp+skip (block-uniform).
  int roff[5];
  bool rok[5];
#pragma unroll
  for (int r = 0; r < 5; r++) {
    int row = 4 * y - 2 + r;
    rok[r] = (row >= 0);
    roff[r] = (row < 0 ? 0 : row) * HW;
  }

  for (int cc4 = 0; cc4 < 16; cc4 += 4) {
    int ci = ci0 + cc4;
    const float* pc[4];
#pragma unroll
    for (int c = 0; c < 4; c++) pc[c] = cen + (size_t)(b * CC + ci + c) * 65536 + 4 * x;
    float4 A[4][5], B[4][5];
#pragma unroll
    for (int c = 0; c < 4; c++) {
#pragma unroll
      for (int r = 0; r < 5; r++) {
        A[c][r] = (x > 0) ? *(const float4*)(pc[c] + roff[r] - 4) : z4;  // 4x-4..4x-1
        B[c][r] = *(const float4*)(pc[c] + roff[r]);                     // 4x..4x+3
      }
    }
#pragma unroll
    for (int r = 0; r < 5; r++) {
      if (!rok[r]) continue;  // block-uniform (only y==0, r<2)
#pragma unroll
      for (int c = 0; c < 4; c++) {
        const float* wa = tW + (co0 * CC + ci + c) * 25 + r * 5;  // uniform -> s_load
        const float* wb = wa + CC * 25;                           // (co0+1, ci+c)
        acc0 += wa[0] * A[c][r].z + wa[1] * A[c][r].w + wa[2] * B[c][r].x +
                wa[3] * B[c][r].y + wa[4] * B[c][r].z;
        acc1 += wb[0] * A[c][r].z + wb[1] * A[c][r].w + wb[2] * B[c][r].x +
                wb[3] * B[c][r].y + wb[4] * B[c][r].z;
      }
    }
  }

  if (cihalf == 1) {  // wave-uniform branch
    part[copair][0][x] = acc0;
    part[copair][1][x] = acc1;
  }
  __syncthreads();
  if (cihalf == 0) {
    acc0 += part[copair][0][x];
    acc1 += part[copair][1][x];
    kv[((b * CC + co0) * KVW + y) * KVW + x] = acc0 + tB[co0];
    kv[((b * CC + co0 + 1) * KVW + y) * KVW + x] = acc1 + tB[co0 + 1];
  }
}

// ---------------- K2i: per-(b,c,i) partials D[8], M[8], Q2 (round-14 verbatim) --------
__device__ inline float wred64(float v) {
#pragma unroll
  for (int off = 1; off < 64; off <<= 1) v += __shfl_xor(v, off);
  return v;
}

__global__ __launch_bounds__(1024) void k2i_partial(const float* __restrict__ kv,
                                                    const float* __restrict__ qW,
                                                    const float* __restrict__ kW,
                                                    float* __restrict__ pars) {
  __shared__ alignas(16) float kl[4096];  // full 64x64 k_i map (16 KB), no halo
  __shared__ float wredl[16][18];         // per-wave: D[8], M[8], Q2[16]
  int bid = blockIdx.x;  // 192 = bc(64) * 3 + i
  int bc = bid / 3, i = bid - bc * 3;
  int b = bc >> 5, c = bc & 31;
  int tid = threadIdx.x;
  int lane = tid & 63, w = tid >> 6;  // w 0..15
  int xx = tid & 63;
  int ybase = tid >> 6;  // thread's rows are r*16 + ybase

  float qreg[4];
#pragma unroll
  for (int r = 0; r < 4; r++) {
    int px = r * 1024 + tid;  // row = r*16 + ybase, col = xx
    float q = 0.f, kk = 0.f;
    for (int ci = 0; ci < CC; ci++) {
      float val = kv[(b * CC + ci) * 4096 + px];
      q += qW[c * CC + ci] * val;
      kk += kW[(i * CC + c) * CC + ci] * val;
    }
    qreg[r] = q;
    kl[px] = kk;
  }
  __syncthreads();

  float q2 = 0.f;
#pragma unroll
  for (int r = 0; r < 4; r++) q2 += qreg[r] * qreg[r];
  q2 = wred64(q2);
  if (lane == 0) wredl[w][16] = q2;

  constexpr int DYt[8] = {-1, -1, -1, 0, 1, 1, 1, 0};
  constexpr int DXt[8] = {-1, 0, 1, 1, 1, 0, -1, -1};
  const int d = 1 << i;
#pragma unroll
  for (int n = 0; n < 8; n++) {
    const int dy = DYt[n], dx = DXt[n];
    int xn = xx + dx * d;
    bool xok = (xn >= 0 && xn < KVW);
    float dacc = 0.f, macc = 0.f;
#pragma unroll
    for (int r = 0; r < 4; r++) {
      int yy = r * 16 + ybase;
      int px = yy * KVW + xx;
      float kc = kl[px];
      int yn = yy + dy * d;
      float kn = (xok && yn >= 0 && yn < KVW) ? kl[yn * KVW + xn] : 0.f;
      float df = kc - kn;
      dacc += qreg[r] * df;
      macc += df * df;
    }
    dacc = wred64(dacc);
    macc = wred64(macc);
    if (lane == 0) {
      wredl[w][n] = dacc;
      wredl[w][8 + n] = macc;
    }
  }
  __syncthreads();

  float* pp = pars + (size_t)bid * 32;
  if (tid < 8) {
    float D = 0.f, M = 0.f;
    for (int w2 = 0; w2 < 16; w2++) {
      D += wredl[w2][tid];
      M += wredl[w2][8 + tid];
    }
    pp[tid] = D;
    pp[8 + tid] = M;
  }
  if (tid == 0) {
    float Q = 0.f;
    for (int w2 = 0; w2 < 16; w2++) Q += wredl[w2][16];
    pp[16] = Q;
  }
}

// ---------------- K2f: finalize scores [2,32,24] (round-14 verbatim) ----------
__global__ __launch_bounds__(64) void k2f_finalize(const float* __restrict__ pars,
                                                   float* __restrict__ scores) {
  __shared__ float srl[24];
  int bc = blockIdx.x;  // 64 = b*32 + c
  int t = threadIdx.x;
  if (t < 24) {
    int i = t >> 3, n = t & 7;
    const float* pp = pars + (size_t)(bc * 3 + i) * 32;
    float D = pp[n];
    float M = pp[8 + n];
    float Q = pars[(size_t)(bc * 3) * 32 + 16];  // Q2 identical across i; use i=0's
    float sr = D / (fmaxf(sqrtf(M), 1e-12f) * fmaxf(sqrtf(Q), 1e-12f));
    srl[t] = sr;
  }
  __syncthreads();
  if (t < 24) {
    float r2 = 0.f;
    for (int j = 0; j < 24; j++) r2 += srl[j] * srl[j];
    scores[bc * 24 + t] = srl[t] / fmaxf(sqrtf(r2), 1e-12f);
  }
}

// ---------------- K3a: v[i][b][c][px], bf16, 2 px/thread (round-14 verbatim) ----------
__global__ __launch_bounds__(256) void k3a_values(const float* __restrict__ cen,
                                                  const float* __restrict__ vW,
                                                  __hip_bfloat16* __restrict__ v) {
  int bid = blockIdx.x;  // 1024 = b(2) x blk(512)
  int b = bid >> 9, blk = bid & 511;
  int tid = threadIdx.x;
  int lane = tid & 63;
  int cg = __builtin_amdgcn_readfirstlane(tid >> 6);  // wave-uniform c group (8 c)
  int px = blk * 128 + lane * 2;

  float2 cr[CC];
#pragma unroll
  for (int ci = 0; ci < CC; ci++)
    cr[ci] = *(const float2*)(cen + (size_t)(b * CC + ci) * 65536 + px);

#pragma unroll
  for (int i = 0; i < 3; i++) {
#pragma unroll
    for (int cc = 0; cc < 8; cc++) {
      int c = cg * 8 + cc;
      const float* wp = vW + (i * CC + c) * CC;  // uniform -> s_load
      float a0 = 0.f, a1 = 0.f;
#pragma unroll
      for (int ci = 0; ci < CC; ci++) {
        a0 += wp[ci] * cr[ci].x;
        a1 += wp[ci] * cr[ci].y;
      }
      __hip_bfloat16 h0 = __float2bfloat16(a0);
      __hip_bfloat16 h1 = __float2bfloat16(a1);
      unsigned int pk = (unsigned int)(*(unsigned short*)&h0) |
                        ((unsigned int)(*(unsigned short*)&h1) << 16);
      *(unsigned int*)((unsigned short*)v + (((size_t)((i * 2 + b) * CC + c)) << 16) +
                       px) = pk;
    }
  }
}

// ---------------- K3b: combine taps + out conv + BN + ReLU (round-14 verbatim) --------
__global__ __launch_bounds__(256) void k3b_combine(const __hip_bfloat16* __restrict__ v,
                                                   const float* __restrict__ scores,
                                                   const float* __restrict__ oW,
                                                   const float* __restrict__ gamma,
                                                   const float* __restrict__ beta,
                                                   const float* __restrict__ mean,
                                                   const float* __restrict__ var,
                                                   float* __restrict__ out) {
  __shared__ alignas(16) float vt[3 * 24 * 24 * 4];  // [i][r][col][cp] halo-4 tiles
  __shared__ alignas(16) float sl[27][32];           // 0..23: s[j][c]; 24..26: S_i[c]
  __shared__ alignas(16) float owl[32][32];          // [co][c]
  __shared__ float bns[32], bnb[32];

  int bid = blockIdx.x;
  int b = bid >> 8, tile = bid & 255;
  int ty = tile >> 4, tx = tile & 15;
  int tid = threadIdx.x;
  int ly = tid >> 4, lx = tid & 15;

  for (int f = tid; f < 24 * 32; f += 256) {
    int j = f >> 5, c = f & 31;
    sl[j][c] = scores[(b * CC + c) * 24 + j];
  }
  for (int f = tid; f < 1024; f += 256) owl[f >> 5][f & 31] = oW[f];
  if (tid < 32) {
    float inv = rsqrtf(var[tid] + 1e-5f);
    float sc = gamma[tid] * inv;
    bns[tid] = sc;
    bnb[tid] = beta[tid] - mean[tid] * sc;
  }
  __syncthreads();
  if (tid < 32) {
#pragma unroll
    for (int i = 0; i < 3; i++) {
      float s = 0.f;
      for (int n = 0; n < 8; n++) s += sl[i * 8 + n][tid];
      sl[24 + i][tid] = s;
    }
  }

  int ldsoff[4], pxoff[4], ibase[4];
  bool okp[4];
#pragma unroll
  for (int it = 0; it < 4; it++) {
    int p = tid + it * 256;
    bool act = (p < 864);
    int pp = act ? p : 0;
    int i = pp / 288;
    int rem = pp - i * 288;
    int r = rem / 12;
    int col = (rem - r * 12) * 2;
    int gy = ty * 16 + r - 4, gx = tx * 16 + col - 4;
    okp[it] = act && gy >= 0 && gy < HW && gx >= 0 && gx < HW;
    pxoff[it] = gy * HW + gx;
    ibase[it] = (i * 2 + b) * CC;
    ldsoff[it] = ((i * 24 + r) * 24 + col) * 4;
  }

  constexpr int DYt[8] = {-1, -1, -1, 0, 1, 1, 1, 0};
  constexpr int DXt[8] = {-1, 0, 1, 1, 1, 0, -1, -1};

  float acc[32];
#pragma unroll
  for (int co = 0; co < 32; co++) acc[co] = 0.f;

  unsigned int pf[4][4];
  const unsigned short* vs = (const unsigned short*)v;

#pragma unroll
  for (int it = 0; it < 4; it++)
#pragma unroll
    for (int cp = 0; cp < 4; cp++)
      pf[it][cp] = okp[it]
                       ? *(const unsigned int*)(vs + (((size_t)(ibase[it] + cp)) << 16) +
                                                pxoff[it])
                       : 0u;

  for (int cg = 0; cg < 8; cg++) {
    __syncthreads();
#pragma unroll
    for (int it = 0; it < 4; it++) {
      if (it == 3 && tid >= 96) continue;  // p >= 864
      float4 lo, hi;
      lo.x = __uint_as_float(pf[it][0] << 16);
      lo.y = __uint_as_float(pf[it][1] << 16);
      lo.z = __uint_as_float(pf[it][2] << 16);
      lo.w = __uint_as_float(pf[it][3] << 16);
      hi.x = __uint_as_float(pf[it][0] & 0xffff0000u);
      hi.y = __uint_as_float(pf[it][1] & 0xffff0000u);
      hi.z = __uint_as_float(pf[it][2] & 0xffff0000u);
      hi.w = __uint_as_float(pf[it][3] & 0xffff0000u);
      *(float4*)&vt[ldsoff[it]] = lo;
      *(float4*)&vt[ldsoff[it] + 4] = hi;
    }
    if (cg < 7) {
      int cb = (cg + 1) * 4;
#pragma unroll
      for (int it = 0; it < 4; it++)
#pragma unroll
        for (int cp = 0; cp < 4; cp++)
          pf[it][cp] = okp[it] ? *(const unsigned int*)(vs +
                                                        (((size_t)(ibase[it] + cb + cp))
                                                         << 16) +
                                                        pxoff[it])
                               : 0u;
    }
    __syncthreads();

    float4 pre = {0.f, 0.f, 0.f, 0.f};
#pragma unroll
    for (int i = 0; i < 3; i++) {
      const int d = 1 << i;
      float4 S4 = *(const float4*)&sl[24 + i][cg * 4];
      float4 ctr = *(const float4*)&vt[((i * 24 + (ly + 4)) * 24 + (lx + 4)) * 4];
      pre.x += S4.x * ctr.x;
      pre.y += S4.y * ctr.y;
      pre.z += S4.z * ctr.z;
      pre.w += S4.w * ctr.w;
#pragma unroll
      for (int n = 0; n < 8; n++) {
        float4 sj = *(const float4*)&sl[i * 8 + n][cg * 4];
        float4 nb = *(const float4*)&vt[((i * 24 + (ly + 4 + DYt[n] * d)) * 24 +
                                         (lx + 4 + DXt[n] * d)) * 4];
        pre.x -= sj.x * nb.x;
        pre.y -= sj.y * nb.y;
        pre.z -= sj.z * nb.z;
        pre.w -= sj.w * nb.w;
      }
    }
#pragma unroll
    for (int co = 0; co < 32; co++) {
      float4 ow = *(const float4*)&owl[co][cg * 4];
      acc[co] += ow.x * pre.x + ow.y * pre.y + ow.z * pre.z + ow.w * pre.w;
    }
  }

  int gy = ty * 16 + ly, gx = tx * 16 + lx;
#pragma unroll
  for (int co = 0; co < 32; co++) {
    float val = acc[co] * bns[co] + bnb[co];
    out[((size_t)(b * CC + co) << 16) + gy * HW + gx] = fmaxf(val, 0.f);
  }
}

extern "C" void kernel_launch(void* const* d_in, const int* in_sizes, int n_in,
                              void* d_out, int out_size, void* d_ws, size_t ws_size,
                              hipStream_t stream) {
  const float* cen = (const float*)d_in[0];
  const float* trans_W = (const float*)d_in[1];
  const float* trans_b = (const float*)d_in[2];
  const float* query_W = (const float*)d_in[3];
  const float* value_W = (const float*)d_in[4];
  const float* key_W = (const float*)d_in[5];
  const float* out_W = (const float*)d_in[6];
  const float* bn_gamma = (const float*)d_in[7];
  const float* bn_beta = (const float*)d_in[8];
  const float* bn_mean = (const float*)d_in[9];
  const float* bn_var = (const float*)d_in[10];
  float* out = (float*)d_out;

  // workspace layout — identical to round-14 passing:
  //   kv     [0,        524288)
  //   scores [524288,   530432)
  //   v      [532480,   25698304)  (bf16)
  //   pars   [25673728, 25698304)  -- aliases v tail; consumed by k2f before k3a.
  float* kv = (float*)d_ws;
  float* scores = (float*)((char*)d_ws + 524288);
  __hip_bfloat16* v = (__hip_bfloat16*)((char*)d_ws + 532480);
  float* pars = (float*)((char*)d_ws + 25673728);

  k1_trans<<<1024, 256, 0, stream>>>(cen, trans_W, trans_b, kv);
  k2i_partial<<<192, 1024, 0, stream>>>(kv, query_W, key_W, pars);
  k2f_finalize<<<64, 64, 0, stream>>>(pars, scores);
  k3a_values<<<1024, 256, 0, stream>>>(cen, value_W, v);  // clobbers pars (ok)
  k3b_combine<<<512, 256, 0, stream>>>(v, scores, out_W, bn_gamma, bn_beta, bn_mean,
                                       bn_var, out);
}